// Round 21
// baseline (508.889 us; speedup 1.0000x reference)
//
#include <hip/hip_runtime.h>
#include <hip/hip_bf16.h>
#include <math.h>

// Problem constants (from reference)
#define B_SZ   128
#define HDIM   256
#define NG     1280     // 5*H
#define NNODES 1023
#define VOCAB  2048

typedef unsigned int uint32;
typedef short  short8v  __attribute__((ext_vector_type(8)));   // 8 x bf16 (4 VGPR)
typedef float  float4v  __attribute__((ext_vector_type(4)));   // MFMA C/D frag

__device__ __forceinline__ float sigm(float x) {
    return 1.0f / (1.0f + __expf(-x));
}
__device__ __forceinline__ float tanh_fast(float x) {
    return 2.0f / (1.0f + __expf(-2.0f * x)) - 1.0f;
}
__device__ __forceinline__ float bf2f(unsigned short u) {
    return __uint_as_float(((uint32)u) << 16);
}
__device__ __forceinline__ unsigned short f2bf(float f) {
    uint32 x = __float_as_uint(f);
    uint32 r = (x + 0x7FFFu + ((x >> 16) & 1u)) >> 16;   // RNE
    return (unsigned short)r;
}

// Async 16B/lane global->LDS DMA. LDS dest = wave-uniform base + lane*16.
__device__ __forceinline__ void dma16(const unsigned short* gptr, unsigned short* lptr) {
    __builtin_amdgcn_global_load_lds(
        (const __attribute__((address_space(1))) void*)gptr,
        (__attribute__((address_space(3))) void*)lptr, 16, 0, 0);
}

// ---------------------------------------------------------------------------
// embb = bf16(emb) : 2048 x 256.  A-operand for the table builders + levels' x.
// ---------------------------------------------------------------------------
__global__ __launch_bounds__(256) void embb_kernel(
    const float* __restrict__ emb, unsigned short* __restrict__ embb)
{
    const int t = blockIdx.x * 256 + threadIdx.x;
    const float4 v0 = *(const float4*)(emb + (size_t)t * 8);
    const float4 v1 = *(const float4*)(emb + (size_t)t * 8 + 4);
    short8v o;
    o[0] = (short)f2bf(v0.x); o[1] = (short)f2bf(v0.y);
    o[2] = (short)f2bf(v0.z); o[3] = (short)f2bf(v0.w);
    o[4] = (short)f2bf(v1.x); o[5] = (short)f2bf(v1.y);
    o[6] = (short)f2bf(v1.z); o[7] = (short)f2bf(v1.w);
    *(short8v*)(embb + (size_t)t * 8) = o;
}

// ---------------------------------------------------------------------------
// WTf: fragment-ready bf16 repack of [Ul;Ur;Wx] (K=768, N=1280) for MFMA B.
// short8 index = (ng*24 + ks)*64 + lane ; lane = q*16 + c
//   holds B[k = ks*32 + q*8 + j][col = ng*16 + c],  j = 0..7
// ---------------------------------------------------------------------------
__global__ __launch_bounds__(256) void prep_wtf(
    const float* __restrict__ Ul, const float* __restrict__ Ur,
    const float* __restrict__ Wx, unsigned short* __restrict__ WTf)
{
    const int t = blockIdx.x * 256 + threadIdx.x;   // 0..122879
    const int l = t & 63;
    const int q = l >> 4, c = l & 15;
    const int ks = (t >> 6) % 24;
    const int ng = t / (24 * 64);                    // 0..79
    const int col = ng * 16 + c;
    const int k = ks * 32 + q * 8;
    const float* src = (k < 256) ? (Ul + (size_t)k * NG + col)
                     : (k < 512) ? (Ur + (size_t)(k - 256) * NG + col)
                                 : (Wx + (size_t)(k - 512) * NG + col);
    short8v v;
    #pragma unroll
    for (int j = 0; j < 8; ++j) v[j] = (short)f2bf(src[(size_t)j * NG]);
    *(short8v*)(WTf + (size_t)t * 8) = v;
}

// ---------------------------------------------------------------------------
// gemm_tab: O[2048][1280] = bf16( A(2048x256) @ Wsec(256x1280) [+ bias] ).
// Wsec = ks_base0 + 8*blockIdx.z (0=Ul, 8=Ur, 16=Wx); O = z ? O1 : O0.
// TAB=true also computes the leaf h/c tables in-epilogue from acc.
// RT=2 (32-row tiles): grid TAB 256 blocks, HU 512 -- fills the machine.
// ---------------------------------------------------------------------------
template <bool TAB, int RT>
__global__ __launch_bounds__(256, 2) void gemm_tab(
    const unsigned short* __restrict__ WTf, const unsigned short* __restrict__ A,
    const float* __restrict__ bias, unsigned short* __restrict__ O0,
    unsigned short* __restrict__ O1,
    unsigned short* __restrict__ Hleaf, unsigned short* __restrict__ Cleaf,
    const int ks_base0)
{
    constexpr int M   = RT * 16;        // rows per block
    constexpr int CPW = RT / 2 ? RT / 2 : 1;   // staging chunks per wave
    __shared__ __align__(16) unsigned short Ab[2][RT * 1024];   // dbuf: M rows x 64 k
    __shared__ __align__(16) unsigned short wbE[RT * 5120];     // 5 gates x M rows x 64 cols

    const int tid  = threadIdx.x;
    const int lane = tid & 63;
    const int w    = tid >> 6;                  // 0..3 = col-tile
    const int quad = lane >> 4, col15 = lane & 15;
    const int jt = blockIdx.x;
    const int rowBase = blockIdx.y * M;         // A row
    const int jbase   = jt * 64;
    const int ks_base = ks_base0 + (int)blockIdx.z * 8;
    unsigned short* O = blockIdx.z ? O1 : O0;

    const unsigned short* agp[CPW];
    unsigned short* ldst[CPW];
    #pragma unroll
    for (int t = 0; t < CPW; ++t) {
        const int ch = CPW * w + t, sub = ch / RT, rt = ch % RT;
        const int srow = rowBase + rt * 16 + col15;
        agp[t]  = A + (size_t)srow * HDIM + sub * 32 + quad * 8;
        ldst[t] = &Ab[0][0] + ch * 512;
    }

    const short8v* WTfv = (const short8v*)WTf;
    uint32 boff[5];
    #pragma unroll
    for (int g = 0; g < 5; ++g)
        boff[g] = (uint32)(((g * 16 + jt * 4 + w) * 24 + ks_base) * 64 + lane);

    float4v acc[RT][5];
    #pragma unroll
    for (int rt = 0; rt < RT; ++rt)
        #pragma unroll
        for (int g = 0; g < 5; ++g)
            #pragma unroll
            for (int e = 0; e < 4; ++e) acc[rt][g][e] = 0.0f;

    #pragma unroll
    for (int t = 0; t < CPW; ++t) dma16(agp[t], ldst[t]);
    __syncthreads();

    #pragma unroll
    for (int s = 0; s < 4; ++s) {
        if (s < 3) {
            #pragma unroll
            for (int t = 0; t < CPW; ++t)
                dma16(agp[t] + (s + 1) * 64, ldst[t] + ((s + 1) & 1) * (RT * 1024));
        }
        #pragma unroll
        for (int sub = 0; sub < 2; ++sub) {
            short8v bf[5];
            #pragma unroll
            for (int g = 0; g < 5; ++g) bf[g] = WTfv[boff[g] + (s * 2 + sub) * 64];
            #pragma unroll
            for (int rt = 0; rt < RT; ++rt) {
                const short8v af = *(const short8v*)&Ab[s & 1][(sub * RT + rt) * 512 + lane * 8];
                #pragma unroll
                for (int g = 0; g < 5; ++g)
                    acc[rt][g] = __builtin_amdgcn_mfma_f32_16x16x32_bf16(
                        af, bf[g], acc[rt][g], 0, 0, 0);
            }
        }
        __syncthreads();
    }

    const int jl = w * 16 + col15;
    const int j  = jbase + jl;
    float bz[5];
    #pragma unroll
    for (int g = 0; g < 5; ++g) bz[g] = bias ? bias[g * 256 + j] : 0.0f;
    const int jchunk = jl >> 3, jpos = jl & 7;

    if (TAB) {
        // Leaf h/c tables directly from acc (gi=g0, go=g3, gu=g4).
        #pragma unroll
        for (int rt = 0; rt < RT; ++rt) {
            #pragma unroll
            for (int reg = 0; reg < 4; ++reg) {
                const int rr = rt * 16 + quad * 4 + reg;
                const float gi = acc[rt][0][reg] + bz[0];
                const float go = acc[rt][3][reg] + bz[3];
                const float gu = acc[rt][4][reg] + bz[4];
                const float c = sigm(gi) * tanh_fast(gu);
                const float h = sigm(go) * tanh_fast(c);
                Hleaf[(size_t)(rowBase + rr) * HDIM + j] = f2bf(h);
                Cleaf[(size_t)(rowBase + rr) * HDIM + j] = f2bf(c);
            }
        }
    }

    #pragma unroll
    for (int rt = 0; rt < RT; ++rt) {
        #pragma unroll
        for (int reg = 0; reg < 4; ++reg) {
            const int rr = rt * 16 + quad * 4 + reg;
            const int roff = ((jchunk + 2 * quad) & 7) * 8 + jpos;  // (rr>>2)&3==quad
            #pragma unroll
            for (int g = 0; g < 5; ++g)
                wbE[(g * M + rr) * 64 + roff] = f2bf(acc[rt][g][reg] + bz[g]);
        }
    }
    __syncthreads();

    #pragma unroll
    for (int k2 = 0; k2 < RT * 5 / 2; ++k2) {       // 5*M*8/256 iterations
        const int c = tid + k2 * 256;                // short8 index
        const int g = c / (M * 8), rr = (c >> 3) & (M - 1), u = c & 7;
        const int ru = (u + 2 * ((rr >> 2) & 3)) & 7;
        const short8v v = *(const short8v*)&wbE[(g * M + rr) * 64 + ru * 8];
        *(short8v*)(O + (size_t)(rowBase + rr) * NG + g * 256 + jbase + u * 8) = v;
    }
}

// ---------------------------------------------------------------------------
// leafcell: level d=8 WITHOUT a GEMM.  gates = HUl[tokL] + HUr[tokR] +
// EWb[tokN] (bias inside EWb) -> LSTM cell with cl/cr from Cleaf.
// 2 col-octets per thread (j, j+128): 2x loads in flight per thread.
// ---------------------------------------------------------------------------
__global__ __launch_bounds__(256) void leafcell_kernel(
    const int* __restrict__ tokens,
    const unsigned short* __restrict__ HUl, const unsigned short* __restrict__ HUr,
    const unsigned short* __restrict__ EWb, const unsigned short* __restrict__ Cleaf,
    unsigned short* __restrict__ hdst, unsigned short* __restrict__ cdst)
{
    const int t = blockIdx.x * 256 + threadIdx.x;   // 0..524287
    const int row = t >> 4;                          // 0..32767 = b*256 + i
    const int j0  = (t & 15) * 8;                    // first octet; second = j0+128
    const int b = row >> 8, i = row & 255;
    const int tokN = tokens[b * NNODES + 255 + i];
    const int tokL = tokens[b * NNODES + 511 + 2 * i];
    const int tokR = tokens[b * NNODES + 512 + 2 * i];

    const unsigned short* pl = HUl + (size_t)tokL * NG + j0;
    const unsigned short* pr = HUr + (size_t)tokR * NG + j0;
    const unsigned short* pn = EWb + (size_t)tokN * NG + j0;

    float g5[5][2][8];
    #pragma unroll
    for (int g = 0; g < 5; ++g) {
        #pragma unroll
        for (int h2 = 0; h2 < 2; ++h2) {
            const short8v vl = *(const short8v*)(pl + g * 256 + h2 * 128);
            const short8v vr = *(const short8v*)(pr + g * 256 + h2 * 128);
            const short8v vn = *(const short8v*)(pn + g * 256 + h2 * 128);
            #pragma unroll
            for (int e = 0; e < 8; ++e)
                g5[g][h2][e] = bf2f((unsigned short)vl[e]) + bf2f((unsigned short)vr[e])
                             + bf2f((unsigned short)vn[e]);
        }
    }
    #pragma unroll
    for (int h2 = 0; h2 < 2; ++h2) {
        const short8v cl8 = *(const short8v*)(Cleaf + (size_t)tokL * HDIM + j0 + h2 * 128);
        const short8v cr8 = *(const short8v*)(Cleaf + (size_t)tokR * HDIM + j0 + h2 * 128);
        short8v ho, co;
        #pragma unroll
        for (int e = 0; e < 8; ++e) {
            const float ii = sigm(g5[0][h2][e]), fl = sigm(g5[1][h2][e]);
            const float fr = sigm(g5[2][h2][e]), oo = sigm(g5[3][h2][e]);
            const float uu = tanh_fast(g5[4][h2][e]);
            const float c = ii * uu + fl * bf2f((unsigned short)cl8[e])
                                    + fr * bf2f((unsigned short)cr8[e]);
            const float h = oo * tanh_fast(c);
            co[e] = (short)f2bf(c);
            ho[e] = (short)f2bf(h);
        }
        *(short8v*)(hdst + (size_t)row * HDIM + j0 + h2 * 128) = ho;
        *(short8v*)(cdst + (size_t)row * HDIM + j0 + h2 * 128) = co;
    }
}

// ---------------------------------------------------------------------------
// Levels d=7,6: K=768 fold [hl|hr|x]@[Ul;Ur;Wx], BK=256 (3 steps).
// Best-measured kernel for the big levels (R16/R18/R20: d=7 56.5-59 us).
// SWZ=true (d=7): 1D grid swizzle -- jt-mates co-XCD AND co-resident.
// SWZ=false (d=6): 2D grid (rowTile, jt).
// ---------------------------------------------------------------------------
template <bool SWZ>
__global__ __launch_bounds__(256, 1) void level_fold(
    const unsigned short* __restrict__ WTf, const int* __restrict__ tokens,
    const unsigned short* __restrict__ embb,
    const unsigned short* __restrict__ hsrc, const unsigned short* __restrict__ csrc,
    const float* __restrict__ bias,
    unsigned short* __restrict__ hdst, unsigned short* __restrict__ cdst,
    float* __restrict__ out, const int d)
{
    const int n = 1 << d;

    __shared__ __align__(16) unsigned short Ab[2][16384];   // 64 KB: dbuf 64r x 256k

    const int tid  = threadIdx.x;
    const int lane = tid & 63;
    const int w    = tid >> 6;
    const int quad = lane >> 4, col15 = lane & 15;

    int jt, rowTile;
    if (SWZ) {
        const int L = blockIdx.x;
        jt      = (L >> 3) & 3;
        rowTile = (L >> 5) * 8 + (L & 7);
    } else {
        jt      = blockIdx.y;
        rowTile = blockIdx.x;
    }
    const int rowBase = rowTile * 64;
    const int jbase   = jt * 64;

    // Base byte offsets per row-tile (k-sub term added at use: sub*64 bytes).
    uint32 oL[4], oN[4];
    #pragma unroll
    for (int t = 0; t < 4; ++t) {
        const int srow = rowBase + t * 16 + col15;
        const int b = srow >> d, i = srow & (n - 1);
        oN[t] = (uint32)tokens[b * NNODES + (n - 1) + i] * 512u + (uint32)(quad * 16);
        oL[t] = (uint32)(2 * srow) * 512u + (uint32)(quad * 16);
    }
    const char* hb = (const char*)hsrc;
    const char* xb = (const char*)embb;

    const short8v* WTfv = (const short8v*)WTf;
    uint32 boff[5];
    #pragma unroll
    for (int g = 0; g < 5; ++g)
        boff[g] = ((g * 16 + jt * 4 + w) * 24) * 64 + lane;   // full K=768

    const int jl = w * 16 + col15;
    const int j  = jbase + jl;
    float bz[5];
    #pragma unroll
    for (int g = 0; g < 5; ++g) bz[g] = bias[g * 256 + j];

    float4v acc[4][5];
    #pragma unroll
    for (int rt = 0; rt < 4; ++rt)
        #pragma unroll
        for (int g = 0; g < 5; ++g)
            #pragma unroll
            for (int e = 0; e < 4; ++e) acc[rt][g][e] = 0.0f;

    // Staging: per step, 32 chunks (8 k-subs x 4 row-tiles); wave w stages
    // subs {2w, 2w+1}, all 4 rts.  Prologue: step 0 = left-child h.
    {
        #pragma unroll
        for (int t = 0; t < 8; ++t) {
            const int sub = 2 * w + (t >> 2), rt = t & 3;
            dma16((const unsigned short*)(hb + oL[rt] + sub * 64),
                  &Ab[0][0] + (sub * 4 + rt) * 512);
        }
    }
    __syncthreads();

    #pragma unroll
    for (int s = 0; s < 3; ++s) {
        if (s < 2) {
            unsigned short* dstb = &Ab[(s + 1) & 1][0];
            #pragma unroll
            for (int t = 0; t < 8; ++t) {
                const int sub = 2 * w + (t >> 2), rt = t & 3;
                const char* p = (s == 0) ? (hb + oL[rt] + 512 + sub * 64)   // right child
                                         : (xb + oN[rt] + sub * 64);        // x = embb[tok]
                dma16((const unsigned short*)p, dstb + (sub * 4 + rt) * 512);
            }
        }
        #pragma unroll
        for (int sub = 0; sub < 8; ++sub) {
            short8v bf[5];
            #pragma unroll
            for (int g = 0; g < 5; ++g) bf[g] = WTfv[boff[g] + (s * 8 + sub) * 64];
            #pragma unroll
            for (int rt = 0; rt < 4; ++rt) {
                const short8v af = *(const short8v*)&Ab[s & 1][(sub * 4 + rt) * 512 + lane * 8];
                #pragma unroll
                for (int g = 0; g < 5; ++g)
                    acc[rt][g] = __builtin_amdgcn_mfma_f32_16x16x32_bf16(
                        af, bf[g], acc[rt][g], 0, 0, 0);
            }
        }
        __syncthreads();
    }

    float hv[4][4], cv[4][4];
    #pragma unroll
    for (int rt = 0; rt < 4; ++rt) {
        #pragma unroll
        for (int reg = 0; reg < 4; ++reg) {
            const int rr = rt * 16 + quad * 4 + reg;
            const int grow = rowBase + rr;
            const float cl = bf2f(csrc[(size_t)(2 * grow) * HDIM + j]);
            const float cr = bf2f(csrc[(size_t)(2 * grow + 1) * HDIM + j]);
            const float gi  = acc[rt][0][reg] + bz[0];
            const float gfl = acc[rt][1][reg] + bz[1];
            const float gfr = acc[rt][2][reg] + bz[2];
            const float go  = acc[rt][3][reg] + bz[3];
            const float gu  = acc[rt][4][reg] + bz[4];
            const float ii = sigm(gi), fl = sigm(gfl), fr = sigm(gfr), oo = sigm(go);
            const float uu = tanh_fast(gu);
            const float c = ii * uu + fl * cl + fr * cr;
            const float h = oo * tanh_fast(c);
            cv[rt][reg] = c; hv[rt][reg] = h;
        }
    }

    unsigned short* wb = &Ab[0][0];
    const int jchunk = jl >> 3, jpos = jl & 7;
    #pragma unroll
    for (int rt = 0; rt < 4; ++rt) {
        #pragma unroll
        for (int reg = 0; reg < 4; ++reg) {
            const int rr = rt * 16 + quad * 4 + reg;
            const int roff = ((jchunk + 2 * quad) & 7) * 8 + jpos;
            wb[rr * 64 + roff]        = f2bf(hv[rt][reg]);
            wb[4096 + rr * 64 + roff] = f2bf(cv[rt][reg]);
        }
    }
    __syncthreads();
    #pragma unroll
    for (int k2 = 0; k2 < 4; ++k2) {
        const int c = tid + k2 * 256;
        const int arr = c >> 9, rr = (c >> 3) & 63, u = c & 7;
        const int ru = (u + 2 * ((rr >> 2) & 3)) & 7;
        const short8v v = *(const short8v*)(wb + (arr * 4096 + rr * 64 + ru * 8));
        unsigned short* dstp = (arr ? cdst : hdst) +
            (size_t)(rowBase + rr) * HDIM + jbase + u * 8;
        *(short8v*)dstp = v;
    }
}

// ---------------------------------------------------------------------------
// Levels d<=5 (latency regime; all operands L2/L3-resident): BARRIER-FREE
// direct-load kernel.  R21 rationale: at tiny grids the fold kernel's LDS
// round-trip + 3x vmcnt(0)-drain + 64 KB LDS are pure overhead.  The MFMA
// A-frag (row=lane&15, k=ks*32+quad*8+0..7) is loaded straight
// global->register (16B/lane; the 64B line fetched for one quad serves the
// other 3 via L1; sources are cache-resident at these sizes).  No staging,
// no K-loop barriers, LDS 16 KB (writeback swizzle only) -> occupancy
// VGPR-bound ~3 blocks/CU, compiler free to software-pipeline.
// ---------------------------------------------------------------------------
__global__ __launch_bounds__(256, 1) void level_direct(
    const unsigned short* __restrict__ WTf, const int* __restrict__ tokens,
    const unsigned short* __restrict__ embb,
    const unsigned short* __restrict__ hsrc, const unsigned short* __restrict__ csrc,
    const float* __restrict__ bias,
    unsigned short* __restrict__ hdst, unsigned short* __restrict__ cdst,
    float* __restrict__ out, const int d)
{
    const int n = 1 << d;

    __shared__ __align__(16) unsigned short wb[8192];   // 16 KB writeback swizzle

    const int tid  = threadIdx.x;
    const int lane = tid & 63;
    const int w    = tid >> 6;
    const int quad = lane >> 4, col15 = lane & 15;
    const int r16  = lane & 15;

    const int jt      = blockIdx.y;
    const int rowTile = blockIdx.x;
    const int rowBase = rowTile * 64;
    const int jbase   = jt * 64;

    // Per-lane A-fragment base pointers (row = rowBase + rt*16 + r16).
    const unsigned short* pL[4];
    const unsigned short* pX[4];
    #pragma unroll
    for (int rt = 0; rt < 4; ++rt) {
        const int grow = rowBase + rt * 16 + r16;
        const int b = grow >> d, i = grow & (n - 1);
        const int tokN = tokens[b * NNODES + (n - 1) + i];
        pL[rt] = hsrc + (size_t)(2 * grow) * HDIM + quad * 8;   // hr = pL + 256
        pX[rt] = embb + (size_t)tokN * HDIM + quad * 8;
    }

    const short8v* WTfv = (const short8v*)WTf;
    uint32 boff[5];
    #pragma unroll
    for (int g = 0; g < 5; ++g)
        boff[g] = ((g * 16 + jt * 4 + w) * 24) * 64 + lane;   // full K=768

    const int jl = w * 16 + col15;
    const int j  = jbase + jl;
    float bz[5];
    #pragma unroll
    for (int g = 0; g < 5; ++g) bz[g] = bias[g * 256 + j];

    float4v acc[4][5];
    #pragma unroll
    for (int rt = 0; rt < 4; ++rt)
        #pragma unroll
        for (int g = 0; g < 5; ++g)
            #pragma unroll
            for (int e = 0; e < 4; ++e) acc[rt][g][e] = 0.0f;

    #pragma unroll
    for (int ks = 0; ks < 24; ++ks) {
        short8v bf[5];
        #pragma unroll
        for (int g = 0; g < 5; ++g) bf[g] = WTfv[boff[g] + ks * 64];
        #pragma unroll
        for (int rt = 0; rt < 4; ++rt) {
            const unsigned short* ap =
                (ks < 8)  ? (pL[rt] + ks * 32)
              : (ks < 16) ? (pL[rt] + 256 + (ks - 8) * 32)
                          : (pX[rt] + (ks - 16) * 32);
            const short8v af = *(const short8v*)ap;
            #pragma unroll
            for (int g = 0; g < 5; ++g)
                acc[rt][g] = __builtin_amdgcn_mfma_f32_16x16x32_bf16(
                    af, bf[g], acc[rt][g], 0, 0, 0);
        }
    }

    float hv[4][4], cv[4][4];
    #pragma unroll
    for (int rt = 0; rt < 4; ++rt) {
        #pragma unroll
        for (int reg = 0; reg < 4; ++reg) {
            const int rr = rt * 16 + quad * 4 + reg;
            const int grow = rowBase + rr;
            const float cl = bf2f(csrc[(size_t)(2 * grow) * HDIM + j]);
            const float cr = bf2f(csrc[(size_t)(2 * grow + 1) * HDIM + j]);
            const float gi  = acc[rt][0][reg] + bz[0];
            const float gfl = acc[rt][1][reg] + bz[1];
            const float gfr = acc[rt][2][reg] + bz[2];
            const float go  = acc[rt][3][reg] + bz[3];
            const float gu  = acc[rt][4][reg] + bz[4];
            const float ii = sigm(gi), fl = sigm(gfl), fr = sigm(gfr), oo = sigm(go);
            const float uu = tanh_fast(gu);
            const float c = ii * uu + fl * cl + fr * cr;
            const float h = oo * tanh_fast(c);
            cv[rt][reg] = c; hv[rt][reg] = h;
            if (d == 0) out[(size_t)grow * HDIM + j] = h;  // n==1 -> b=row
        }
    }
    if (d == 0) return;   // root level: nothing reads hdst/cdst

    const int jchunk = jl >> 3, jpos = jl & 7;
    #pragma unroll
    for (int rt = 0; rt < 4; ++rt) {
        #pragma unroll
        for (int reg = 0; reg < 4; ++reg) {
            const int rr = rt * 16 + quad * 4 + reg;
            const int roff = ((jchunk + 2 * quad) & 7) * 8 + jpos;
            wb[rr * 64 + roff]        = f2bf(hv[rt][reg]);
            wb[4096 + rr * 64 + roff] = f2bf(cv[rt][reg]);
        }
    }
    __syncthreads();
    #pragma unroll
    for (int k2 = 0; k2 < 4; ++k2) {
        const int c = tid + k2 * 256;
        const int arr = c >> 9, rr = (c >> 3) & 63, u = c & 7;
        const int ru = (u + 2 * ((rr >> 2) & 3)) & 7;
        const short8v v = *(const short8v*)(wb + (arr * 4096 + rr * 64 + ru * 8));
        unsigned short* dstp = (arr ? cdst : hdst) +
            (size_t)(rowBase + rr) * HDIM + jbase + u * 8;
        *(short8v*)dstp = v;
    }
}

// ---------------------------------------------------------------------------
extern "C" void kernel_launch(void* const* d_in, const int* in_sizes, int n_in,
                              void* d_out, int out_size, void* d_ws, size_t ws_size,
                              hipStream_t stream)
{
    const int*   tokens = (const int*)d_in[0];
    const float* emb    = (const float*)d_in[1];
    const float* Wx     = (const float*)d_in[2];
    const float* Ul     = (const float*)d_in[3];
    const float* Ur     = (const float*)d_in[4];
    const float* bias   = (const float*)d_in[5];
    float* out = (float*)d_out;

    const size_t EW_ELEMS  = (size_t)VOCAB * NG;          // also HUl/HUr size
    const size_t EMB_ELEMS = (size_t)VOCAB * HDIM;
    const size_t WTF_ELEMS = (size_t)80 * 24 * 64 * 8;
    const size_t LT_ELEMS  = (size_t)VOCAB * HDIM;        // each of Hleaf, Cleaf
    const size_t SLOT_A    = (size_t)16384 * HDIM;        // d=7,5,3,1 outputs
    const size_t SLOT_B    = (size_t)32768 * HDIM;        // d=8,6,4,2,0 outputs
    const size_t REQUIRED  = (3 * EW_ELEMS + EMB_ELEMS + WTF_ELEMS + 2 * LT_ELEMS
                              + 2 * (SLOT_A + SLOT_B)) * 2;
    if (ws_size < REQUIRED || d_ws == nullptr) return;   // clean fail, not a fault

    char* ws = (char*)d_ws;
    unsigned short* EWb   = (unsigned short*)ws;
    unsigned short* HUl   = EWb + EW_ELEMS;
    unsigned short* HUr   = HUl + EW_ELEMS;
    unsigned short* embb  = HUr + EW_ELEMS;
    unsigned short* WTf   = embb + EMB_ELEMS;
    unsigned short* Hleaf = WTf + WTF_ELEMS;
    unsigned short* Cleaf = Hleaf + LT_ELEMS;
    unsigned short* hA    = Cleaf + LT_ELEMS;
    unsigned short* cA    = hA + SLOT_A;
    unsigned short* hB    = cA + SLOT_A;
    unsigned short* cB    = hB + SLOT_B;

    embb_kernel<<<dim3(256), 256, 0, stream>>>(emb, embb);
    prep_wtf<<<dim3(480), 256, 0, stream>>>(Ul, Ur, Wx, WTf);
    // EWb = x@Wx + b, leaf h/c tables fused; 32-row tiles -> 256 blocks.
    gemm_tab<true, 2><<<dim3(4, 64, 1), 256, 0, stream>>>(
        WTf, embb, bias, EWb, nullptr, Hleaf, Cleaf, 16);
    // HUl = Hleaf@Ul and HUr = Hleaf@Ur in ONE launch; 512 blocks.
    gemm_tab<false, 2><<<dim3(4, 64, 2), 256, 0, stream>>>(
        WTf, Hleaf, nullptr, HUl, HUr, nullptr, nullptr, 0);

    // Level d=8: pure table gather + cell (no GEMM).  Writes B-slot.
    leafcell_kernel<<<dim3(2048), 256, 0, stream>>>(
        tokens, HUl, HUr, EWb, Cleaf, hB, cB);

    // d=7: fold, swizzled 1D grid.  d=6: fold, 2D grid.
    level_fold<true><<<dim3(4 * 256), 256, 0, stream>>>(
        WTf, tokens, embb, hB, cB, bias, hA, cA, out, 7);
    level_fold<false><<<dim3(128, 4), 256, 0, stream>>>(
        WTf, tokens, embb, hA, cA, bias, hB, cB, out, 6);

    // d=5..0: barrier-free direct-load kernel (latency regime).
    for (int d = 5; d >= 0; --d) {
        const int NRB = 2 << d;
        const bool evenD = ((d & 1) == 0);
        const unsigned short* hs = evenD ? hA : hB;
        const unsigned short* cs = evenD ? cA : cB;
        unsigned short* hd = evenD ? hB : hA;
        unsigned short* cd = evenD ? cB : cA;
        level_direct<<<dim3(NRB, 4), 256, 0, stream>>>(
            WTf, tokens, embb, hs, cs, bias, hd, cd, out, d);
    }
}

// Round 22
// 318.076 us; speedup vs baseline: 1.5999x; 1.5999x over previous
//
#include <hip/hip_runtime.h>
#include <hip/hip_bf16.h>
#include <math.h>

// Problem constants (from reference)
#define B_SZ   128
#define HDIM   256
#define NG     1280     // 5*H
#define NNODES 1023
#define VOCAB  2048

typedef unsigned int uint32;
typedef short  short8v  __attribute__((ext_vector_type(8)));   // 8 x bf16 (4 VGPR)
typedef float  float4v  __attribute__((ext_vector_type(4)));   // MFMA C/D frag

__device__ __forceinline__ float sigm(float x) {
    return 1.0f / (1.0f + __expf(-x));
}
__device__ __forceinline__ float tanh_fast(float x) {
    return 2.0f / (1.0f + __expf(-2.0f * x)) - 1.0f;
}
__device__ __forceinline__ float bf2f(unsigned short u) {
    return __uint_as_float(((uint32)u) << 16);
}
__device__ __forceinline__ unsigned short f2bf(float f) {
    uint32 x = __float_as_uint(f);
    uint32 r = (x + 0x7FFFu + ((x >> 16) & 1u)) >> 16;   // RNE
    return (unsigned short)r;
}

// Async 16B/lane global->LDS DMA. LDS dest = wave-uniform base + lane*16.
__device__ __forceinline__ void dma16(const unsigned short* gptr, unsigned short* lptr) {
    __builtin_amdgcn_global_load_lds(
        (const __attribute__((address_space(1))) void*)gptr,
        (__attribute__((address_space(3))) void*)lptr, 16, 0, 0);
}

// ---------------------------------------------------------------------------
// embb = bf16(emb) : 2048 x 256.  A-operand for the table builders + levels' x.
// ---------------------------------------------------------------------------
__global__ __launch_bounds__(256) void embb_kernel(
    const float* __restrict__ emb, unsigned short* __restrict__ embb)
{
    const int t = blockIdx.x * 256 + threadIdx.x;
    const float4 v0 = *(const float4*)(emb + (size_t)t * 8);
    const float4 v1 = *(const float4*)(emb + (size_t)t * 8 + 4);
    short8v o;
    o[0] = (short)f2bf(v0.x); o[1] = (short)f2bf(v0.y);
    o[2] = (short)f2bf(v0.z); o[3] = (short)f2bf(v0.w);
    o[4] = (short)f2bf(v1.x); o[5] = (short)f2bf(v1.y);
    o[6] = (short)f2bf(v1.z); o[7] = (short)f2bf(v1.w);
    *(short8v*)(embb + (size_t)t * 8) = o;
}

// ---------------------------------------------------------------------------
// WTf: fragment-ready bf16 repack of [Ul;Ur;Wx] (K=768, N=1280) for MFMA B.
// short8 index = (ng*24 + ks)*64 + lane ; lane = q*16 + c
//   holds B[k = ks*32 + q*8 + j][col = ng*16 + c],  j = 0..7
// ---------------------------------------------------------------------------
__global__ __launch_bounds__(256) void prep_wtf(
    const float* __restrict__ Ul, const float* __restrict__ Ur,
    const float* __restrict__ Wx, unsigned short* __restrict__ WTf)
{
    const int t = blockIdx.x * 256 + threadIdx.x;   // 0..122879
    const int l = t & 63;
    const int q = l >> 4, c = l & 15;
    const int ks = (t >> 6) % 24;
    const int ng = t / (24 * 64);                    // 0..79
    const int col = ng * 16 + c;
    const int k = ks * 32 + q * 8;
    const float* src = (k < 256) ? (Ul + (size_t)k * NG + col)
                     : (k < 512) ? (Ur + (size_t)(k - 256) * NG + col)
                                 : (Wx + (size_t)(k - 512) * NG + col);
    short8v v;
    #pragma unroll
    for (int j = 0; j < 8; ++j) v[j] = (short)f2bf(src[(size_t)j * NG]);
    *(short8v*)(WTf + (size_t)t * 8) = v;
}

// ---------------------------------------------------------------------------
// gemm_tab: O[2048][1280] = bf16( A(2048x256) @ Wsec(256x1280) [+ bias] ).
// Wsec = ks_base0 + 8*blockIdx.z (0=Ul, 8=Ur, 16=Wx); O = z ? O1 : O0.
// TAB=true also computes the leaf h/c tables in-epilogue from acc.
// RT=2 (32-row tiles): grid TAB 256 blocks, HU 512 -- fills the machine.
// ---------------------------------------------------------------------------
template <bool TAB, int RT>
__global__ __launch_bounds__(256, 2) void gemm_tab(
    const unsigned short* __restrict__ WTf, const unsigned short* __restrict__ A,
    const float* __restrict__ bias, unsigned short* __restrict__ O0,
    unsigned short* __restrict__ O1,
    unsigned short* __restrict__ Hleaf, unsigned short* __restrict__ Cleaf,
    const int ks_base0)
{
    constexpr int M   = RT * 16;        // rows per block
    constexpr int CPW = RT / 2 ? RT / 2 : 1;   // staging chunks per wave
    __shared__ __align__(16) unsigned short Ab[2][RT * 1024];   // dbuf: M rows x 64 k
    __shared__ __align__(16) unsigned short wbE[RT * 5120];     // 5 gates x M rows x 64 cols

    const int tid  = threadIdx.x;
    const int lane = tid & 63;
    const int w    = tid >> 6;                  // 0..3 = col-tile
    const int quad = lane >> 4, col15 = lane & 15;
    const int jt = blockIdx.x;
    const int rowBase = blockIdx.y * M;         // A row
    const int jbase   = jt * 64;
    const int ks_base = ks_base0 + (int)blockIdx.z * 8;
    unsigned short* O = blockIdx.z ? O1 : O0;

    const unsigned short* agp[CPW];
    unsigned short* ldst[CPW];
    #pragma unroll
    for (int t = 0; t < CPW; ++t) {
        const int ch = CPW * w + t, sub = ch / RT, rt = ch % RT;
        const int srow = rowBase + rt * 16 + col15;
        agp[t]  = A + (size_t)srow * HDIM + sub * 32 + quad * 8;
        ldst[t] = &Ab[0][0] + ch * 512;
    }

    const short8v* WTfv = (const short8v*)WTf;
    uint32 boff[5];
    #pragma unroll
    for (int g = 0; g < 5; ++g)
        boff[g] = (uint32)(((g * 16 + jt * 4 + w) * 24 + ks_base) * 64 + lane);

    float4v acc[RT][5];
    #pragma unroll
    for (int rt = 0; rt < RT; ++rt)
        #pragma unroll
        for (int g = 0; g < 5; ++g)
            #pragma unroll
            for (int e = 0; e < 4; ++e) acc[rt][g][e] = 0.0f;

    #pragma unroll
    for (int t = 0; t < CPW; ++t) dma16(agp[t], ldst[t]);
    __syncthreads();

    #pragma unroll
    for (int s = 0; s < 4; ++s) {
        if (s < 3) {
            #pragma unroll
            for (int t = 0; t < CPW; ++t)
                dma16(agp[t] + (s + 1) * 64, ldst[t] + ((s + 1) & 1) * (RT * 1024));
        }
        #pragma unroll
        for (int sub = 0; sub < 2; ++sub) {
            short8v bf[5];
            #pragma unroll
            for (int g = 0; g < 5; ++g) bf[g] = WTfv[boff[g] + (s * 2 + sub) * 64];
            #pragma unroll
            for (int rt = 0; rt < RT; ++rt) {
                const short8v af = *(const short8v*)&Ab[s & 1][(sub * RT + rt) * 512 + lane * 8];
                #pragma unroll
                for (int g = 0; g < 5; ++g)
                    acc[rt][g] = __builtin_amdgcn_mfma_f32_16x16x32_bf16(
                        af, bf[g], acc[rt][g], 0, 0, 0);
            }
        }
        __syncthreads();
    }

    const int jl = w * 16 + col15;
    const int j  = jbase + jl;
    float bz[5];
    #pragma unroll
    for (int g = 0; g < 5; ++g) bz[g] = bias ? bias[g * 256 + j] : 0.0f;
    const int jchunk = jl >> 3, jpos = jl & 7;

    if (TAB) {
        // Leaf h/c tables directly from acc (gi=g0, go=g3, gu=g4).
        #pragma unroll
        for (int rt = 0; rt < RT; ++rt) {
            #pragma unroll
            for (int reg = 0; reg < 4; ++reg) {
                const int rr = rt * 16 + quad * 4 + reg;
                const float gi = acc[rt][0][reg] + bz[0];
                const float go = acc[rt][3][reg] + bz[3];
                const float gu = acc[rt][4][reg] + bz[4];
                const float c = sigm(gi) * tanh_fast(gu);
                const float h = sigm(go) * tanh_fast(c);
                Hleaf[(size_t)(rowBase + rr) * HDIM + j] = f2bf(h);
                Cleaf[(size_t)(rowBase + rr) * HDIM + j] = f2bf(c);
            }
        }
    }

    #pragma unroll
    for (int rt = 0; rt < RT; ++rt) {
        #pragma unroll
        for (int reg = 0; reg < 4; ++reg) {
            const int rr = rt * 16 + quad * 4 + reg;
            const int roff = ((jchunk + 2 * quad) & 7) * 8 + jpos;  // (rr>>2)&3==quad
            #pragma unroll
            for (int g = 0; g < 5; ++g)
                wbE[(g * M + rr) * 64 + roff] = f2bf(acc[rt][g][reg] + bz[g]);
        }
    }
    __syncthreads();

    #pragma unroll
    for (int k2 = 0; k2 < RT * 5 / 2; ++k2) {       // 5*M*8/256 iterations
        const int c = tid + k2 * 256;                // short8 index
        const int g = c / (M * 8), rr = (c >> 3) & (M - 1), u = c & 7;
        const int ru = (u + 2 * ((rr >> 2) & 3)) & 7;
        const short8v v = *(const short8v*)&wbE[(g * M + rr) * 64 + ru * 8];
        *(short8v*)(O + (size_t)(rowBase + rr) * NG + g * 256 + jbase + u * 8) = v;
    }
}

// ---------------------------------------------------------------------------
// leafcell: level d=8 WITHOUT a GEMM.  gates = HUl[tokL] + HUr[tokR] +
// EWb[tokN] (bias inside EWb) -> LSTM cell with cl/cr from Cleaf.
// 2 col-octets per thread (j, j+128): 2x loads in flight per thread.
// ---------------------------------------------------------------------------
__global__ __launch_bounds__(256) void leafcell_kernel(
    const int* __restrict__ tokens,
    const unsigned short* __restrict__ HUl, const unsigned short* __restrict__ HUr,
    const unsigned short* __restrict__ EWb, const unsigned short* __restrict__ Cleaf,
    unsigned short* __restrict__ hdst, unsigned short* __restrict__ cdst)
{
    const int t = blockIdx.x * 256 + threadIdx.x;   // 0..524287
    const int row = t >> 4;                          // 0..32767 = b*256 + i
    const int j0  = (t & 15) * 8;                    // first octet; second = j0+128
    const int b = row >> 8, i = row & 255;
    const int tokN = tokens[b * NNODES + 255 + i];
    const int tokL = tokens[b * NNODES + 511 + 2 * i];
    const int tokR = tokens[b * NNODES + 512 + 2 * i];

    const unsigned short* pl = HUl + (size_t)tokL * NG + j0;
    const unsigned short* pr = HUr + (size_t)tokR * NG + j0;
    const unsigned short* pn = EWb + (size_t)tokN * NG + j0;

    float g5[5][2][8];
    #pragma unroll
    for (int g = 0; g < 5; ++g) {
        #pragma unroll
        for (int h2 = 0; h2 < 2; ++h2) {
            const short8v vl = *(const short8v*)(pl + g * 256 + h2 * 128);
            const short8v vr = *(const short8v*)(pr + g * 256 + h2 * 128);
            const short8v vn = *(const short8v*)(pn + g * 256 + h2 * 128);
            #pragma unroll
            for (int e = 0; e < 8; ++e)
                g5[g][h2][e] = bf2f((unsigned short)vl[e]) + bf2f((unsigned short)vr[e])
                             + bf2f((unsigned short)vn[e]);
        }
    }
    #pragma unroll
    for (int h2 = 0; h2 < 2; ++h2) {
        const short8v cl8 = *(const short8v*)(Cleaf + (size_t)tokL * HDIM + j0 + h2 * 128);
        const short8v cr8 = *(const short8v*)(Cleaf + (size_t)tokR * HDIM + j0 + h2 * 128);
        short8v ho, co;
        #pragma unroll
        for (int e = 0; e < 8; ++e) {
            const float ii = sigm(g5[0][h2][e]), fl = sigm(g5[1][h2][e]);
            const float fr = sigm(g5[2][h2][e]), oo = sigm(g5[3][h2][e]);
            const float uu = tanh_fast(g5[4][h2][e]);
            const float c = ii * uu + fl * bf2f((unsigned short)cl8[e])
                                    + fr * bf2f((unsigned short)cr8[e]);
            const float h = oo * tanh_fast(c);
            co[e] = (short)f2bf(c);
            ho[e] = (short)f2bf(h);
        }
        *(short8v*)(hdst + (size_t)row * HDIM + j0 + h2 * 128) = ho;
        *(short8v*)(cdst + (size_t)row * HDIM + j0 + h2 * 128) = co;
    }
}

// ---------------------------------------------------------------------------
// Levels d=7..0: K=768 fold [hl|hr|x]@[Ul;Ur;Wx], BK=256 (3 steps, one per
// operand: s=0 hl, s=1 hr, s=2 x).  Best-measured kernel (R16/R18/R20:
// 318.6/319.4/320.3 us total; d=7 56.5-59 us).  Final configuration after
// four failed structural attacks (BK deepening: null; 128-row tiles:
// occupancy collapse; shared-B: traffic regression; barrier-free direct:
// uncoalesced loads + co-compile regalloc perturbation).
// 160 MFMA/wave/step covers the 8-chunk prefetch; LDS dbuf 64 KB.
// SWZ=true (d=7): 1D grid swizzle -- jt-mates co-XCD AND co-resident.
// SWZ=false (d<=6): 2D grid (rowTile, jt).
// ---------------------------------------------------------------------------
template <bool SWZ>
__global__ __launch_bounds__(256, 1) void level_fold(
    const unsigned short* __restrict__ WTf, const int* __restrict__ tokens,
    const unsigned short* __restrict__ embb,
    const unsigned short* __restrict__ hsrc, const unsigned short* __restrict__ csrc,
    const float* __restrict__ bias,
    unsigned short* __restrict__ hdst, unsigned short* __restrict__ cdst,
    float* __restrict__ out, const int d)
{
    const int n = 1 << d;

    __shared__ __align__(16) unsigned short Ab[2][16384];   // 64 KB: dbuf 64r x 256k

    const int tid  = threadIdx.x;
    const int lane = tid & 63;
    const int w    = tid >> 6;
    const int quad = lane >> 4, col15 = lane & 15;

    int jt, rowTile;
    if (SWZ) {
        const int L = blockIdx.x;
        jt      = (L >> 3) & 3;
        rowTile = (L >> 5) * 8 + (L & 7);
    } else {
        jt      = blockIdx.y;
        rowTile = blockIdx.x;
    }
    const int rowBase = rowTile * 64;
    const int jbase   = jt * 64;

    // Base byte offsets per row-tile (k-sub term added at use: sub*64 bytes).
    uint32 oL[4], oN[4];
    #pragma unroll
    for (int t = 0; t < 4; ++t) {
        const int srow = rowBase + t * 16 + col15;
        const int b = srow >> d, i = srow & (n - 1);
        oN[t] = (uint32)tokens[b * NNODES + (n - 1) + i] * 512u + (uint32)(quad * 16);
        oL[t] = (uint32)(2 * srow) * 512u + (uint32)(quad * 16);
    }
    const char* hb = (const char*)hsrc;
    const char* xb = (const char*)embb;

    const short8v* WTfv = (const short8v*)WTf;
    uint32 boff[5];
    #pragma unroll
    for (int g = 0; g < 5; ++g)
        boff[g] = ((g * 16 + jt * 4 + w) * 24) * 64 + lane;   // full K=768

    const int jl = w * 16 + col15;
    const int j  = jbase + jl;
    float bz[5];
    #pragma unroll
    for (int g = 0; g < 5; ++g) bz[g] = bias[g * 256 + j];

    float4v acc[4][5];
    #pragma unroll
    for (int rt = 0; rt < 4; ++rt)
        #pragma unroll
        for (int g = 0; g < 5; ++g)
            #pragma unroll
            for (int e = 0; e < 4; ++e) acc[rt][g][e] = 0.0f;

    // Staging: per step, 32 chunks (8 k-subs x 4 row-tiles); wave w stages
    // subs {2w, 2w+1}, all 4 rts.  Prologue: step 0 = left-child h.
    {
        #pragma unroll
        for (int t = 0; t < 8; ++t) {
            const int sub = 2 * w + (t >> 2), rt = t & 3;
            dma16((const unsigned short*)(hb + oL[rt] + sub * 64),
                  &Ab[0][0] + (sub * 4 + rt) * 512);
        }
    }
    __syncthreads();

    #pragma unroll
    for (int s = 0; s < 3; ++s) {
        if (s < 2) {
            unsigned short* dstb = &Ab[(s + 1) & 1][0];
            #pragma unroll
            for (int t = 0; t < 8; ++t) {
                const int sub = 2 * w + (t >> 2), rt = t & 3;
                const char* p = (s == 0) ? (hb + oL[rt] + 512 + sub * 64)   // right child
                                         : (xb + oN[rt] + sub * 64);        // x = embb[tok]
                dma16((const unsigned short*)p, dstb + (sub * 4 + rt) * 512);
            }
        }
        #pragma unroll
        for (int sub = 0; sub < 8; ++sub) {
            short8v bf[5];
            #pragma unroll
            for (int g = 0; g < 5; ++g) bf[g] = WTfv[boff[g] + (s * 8 + sub) * 64];
            #pragma unroll
            for (int rt = 0; rt < 4; ++rt) {
                const short8v af = *(const short8v*)&Ab[s & 1][(sub * 4 + rt) * 512 + lane * 8];
                #pragma unroll
                for (int g = 0; g < 5; ++g)
                    acc[rt][g] = __builtin_amdgcn_mfma_f32_16x16x32_bf16(
                        af, bf[g], acc[rt][g], 0, 0, 0);
            }
        }
        __syncthreads();
    }

    float hv[4][4], cv[4][4];
    #pragma unroll
    for (int rt = 0; rt < 4; ++rt) {
        #pragma unroll
        for (int reg = 0; reg < 4; ++reg) {
            const int rr = rt * 16 + quad * 4 + reg;
            const int grow = rowBase + rr;
            const float cl = bf2f(csrc[(size_t)(2 * grow) * HDIM + j]);
            const float cr = bf2f(csrc[(size_t)(2 * grow + 1) * HDIM + j]);
            const float gi  = acc[rt][0][reg] + bz[0];
            const float gfl = acc[rt][1][reg] + bz[1];
            const float gfr = acc[rt][2][reg] + bz[2];
            const float go  = acc[rt][3][reg] + bz[3];
            const float gu  = acc[rt][4][reg] + bz[4];
            const float ii = sigm(gi), fl = sigm(gfl), fr = sigm(gfr), oo = sigm(go);
            const float uu = tanh_fast(gu);
            const float c = ii * uu + fl * cl + fr * cr;
            const float h = oo * tanh_fast(c);
            cv[rt][reg] = c; hv[rt][reg] = h;
            if (d == 0) out[(size_t)grow * HDIM + j] = h;  // n==1 -> b=row
        }
    }
    if (d == 0) return;   // root level: nothing reads hdst/cdst

    unsigned short* wb = &Ab[0][0];
    const int jchunk = jl >> 3, jpos = jl & 7;
    #pragma unroll
    for (int rt = 0; rt < 4; ++rt) {
        #pragma unroll
        for (int reg = 0; reg < 4; ++reg) {
            const int rr = rt * 16 + quad * 4 + reg;
            const int roff = ((jchunk + 2 * quad) & 7) * 8 + jpos;
            wb[rr * 64 + roff]        = f2bf(hv[rt][reg]);
            wb[4096 + rr * 64 + roff] = f2bf(cv[rt][reg]);
        }
    }
    __syncthreads();
    #pragma unroll
    for (int k2 = 0; k2 < 4; ++k2) {
        const int c = tid + k2 * 256;
        const int arr = c >> 9, rr = (c >> 3) & 63, u = c & 7;
        const int ru = (u + 2 * ((rr >> 2) & 3)) & 7;
        const short8v v = *(const short8v*)(wb + (arr * 4096 + rr * 64 + ru * 8));
        unsigned short* dstp = (arr ? cdst : hdst) +
            (size_t)(rowBase + rr) * HDIM + jbase + u * 8;
        *(short8v*)dstp = v;
    }
}

// ---------------------------------------------------------------------------
extern "C" void kernel_launch(void* const* d_in, const int* in_sizes, int n_in,
                              void* d_out, int out_size, void* d_ws, size_t ws_size,
                              hipStream_t stream)
{
    const int*   tokens = (const int*)d_in[0];
    const float* emb    = (const float*)d_in[1];
    const float* Wx     = (const float*)d_in[2];
    const float* Ul     = (const float*)d_in[3];
    const float* Ur     = (const float*)d_in[4];
    const float* bias   = (const float*)d_in[5];
    float* out = (float*)d_out;

    const size_t EW_ELEMS  = (size_t)VOCAB * NG;          // also HUl/HUr size
    const size_t EMB_ELEMS = (size_t)VOCAB * HDIM;
    const size_t WTF_ELEMS = (size_t)80 * 24 * 64 * 8;
    const size_t LT_ELEMS  = (size_t)VOCAB * HDIM;        // each of Hleaf, Cleaf
    const size_t SLOT_A    = (size_t)16384 * HDIM;        // d=7,5,3,1 outputs
    const size_t SLOT_B    = (size_t)32768 * HDIM;        // d=8,6,4,2,0 outputs
    const size_t REQUIRED  = (3 * EW_ELEMS + EMB_ELEMS + WTF_ELEMS + 2 * LT_ELEMS
                              + 2 * (SLOT_A + SLOT_B)) * 2;
    if (ws_size < REQUIRED || d_ws == nullptr) return;   // clean fail, not a fault

    char* ws = (char*)d_ws;
    unsigned short* EWb   = (unsigned short*)ws;
    unsigned short* HUl   = EWb + EW_ELEMS;
    unsigned short* HUr   = HUl + EW_ELEMS;
    unsigned short* embb  = HUr + EW_ELEMS;
    unsigned short* WTf   = embb + EMB_ELEMS;
    unsigned short* Hleaf = WTf + WTF_ELEMS;
    unsigned short* Cleaf = Hleaf + LT_ELEMS;
    unsigned short* hA    = Cleaf + LT_ELEMS;
    unsigned short* cA    = hA + SLOT_A;
    unsigned short* hB    = cA + SLOT_A;
    unsigned short* cB    = hB + SLOT_B;

    embb_kernel<<<dim3(256), 256, 0, stream>>>(emb, embb);
    prep_wtf<<<dim3(480), 256, 0, stream>>>(Ul, Ur, Wx, WTf);
    // EWb = x@Wx + b, leaf h/c tables fused; 32-row tiles -> 256 blocks.
    gemm_tab<true, 2><<<dim3(4, 64, 1), 256, 0, stream>>>(
        WTf, embb, bias, EWb, nullptr, Hleaf, Cleaf, 16);
    // HUl = Hleaf@Ul and HUr = Hleaf@Ur in ONE launch; 512 blocks.
    gemm_tab<false, 2><<<dim3(4, 64, 2), 256, 0, stream>>>(
        WTf, Hleaf, nullptr, HUl, HUr, nullptr, nullptr, 0);

    // Level d=8: pure table gather + cell (no GEMM).  Writes B-slot.
    leafcell_kernel<<<dim3(2048), 256, 0, stream>>>(
        tokens, HUl, HUr, EWb, Cleaf, hB, cB);

    // d=7: swizzle variant (1D grid).
    level_fold<true><<<dim3(4 * 256), 256, 0, stream>>>(
        WTf, tokens, embb, hB, cB, bias, hA, cA, out, 7);

    // d=6..0: 2D rows-fastest variant.
    for (int d = 6; d >= 0; --d) {
        const int NRB = 2 << d;
        const bool evenD = ((d & 1) == 0);
        const unsigned short* hs = evenD ? hA : hB;
        const unsigned short* cs = evenD ? cA : cB;
        unsigned short* hd = evenD ? hB : hA;
        unsigned short* cd = evenD ? cB : cA;
        level_fold<false><<<dim3(NRB, 4), 256, 0, stream>>>(
            WTf, tokens, embb, hs, cs, bias, hd, cd, out, d);
    }
}